// Round 9
// baseline (100.063 us; speedup 1.0000x reference)
//
#include <hip/hip_runtime.h>
#include <math.h>

// Problem constants: h [B,T,D] fp32, k scalar fp32.
#define BB 8
#define TT 2048
#define DD 512
#define LL 16             // chunk length (t-steps)
#define CC (TT / LL)      // 128 chunks per b
#define D4 (DD / 4)       // 128 float4 lanes = block size
#define SCT 32            // superchunk length (t-steps)
#define NSC (TT / SCT)    // 64 superchunks per b
#define CPS (SCT / LL)    // 2 chunks per superchunk

typedef float floatx4 __attribute__((ext_vector_type(4)));

__device__ __forceinline__ float get_s(const float* kp) {
    float k = *kp;
    return (k > 20.0f) ? k : log1pf(expf(k));   // softplus, stable
}

// ---------------------------------------------------------------------------
// Kernel A: block = (b, superchunk). Streams 32 t-steps of h once; emits
// chunk-level stats (sum S, decayed-end E per 16 t) and superchunk-level
// stats (per 32 t). Grid = 8*64 = 512 blocks x 128 threads (2 blk/CU).
// ---------------------------------------------------------------------------
__global__ __launch_bounds__(D4) void kA_stats(
    const float* __restrict__ h, const float* __restrict__ kp,
    float* __restrict__ csum, float* __restrict__ cend,
    float* __restrict__ ssum, float* __restrict__ send)
{
    const int blk = blockIdx.x;
    const int b = blk / NSC, sc = blk % NSC;
    const int tid = threadIdx.x;
    const float s   = get_s(kp);
    const float a   = expf(-s);
    const float a16 = expf(-s * (float)LL);

    const float4* hp = reinterpret_cast<const float4*>(h)
                     + (size_t)(b * TT + sc * SCT) * D4 + tid;

    float Sx = 0.f, Sy = 0.f, Sz = 0.f, Sw = 0.f;   // superchunk sum
    float Ex = 0.f, Ey = 0.f, Ez = 0.f, Ew = 0.f;   // superchunk decayed end

    #pragma unroll
    for (int j = 0; j < CPS; j++) {
        float sx = 0.f, sy = 0.f, sz = 0.f, sw = 0.f;
        float ex = 0.f, ey = 0.f, ez = 0.f, ew = 0.f;
        #pragma unroll
        for (int i = 0; i < LL; i++) {
            float4 x = hp[(size_t)(j * LL + i) * D4];
            sx += x.x; sy += x.y; sz += x.z; sw += x.w;
            ex = fmaf(a, ex, x.x);
            ey = fmaf(a, ey, x.y);
            ez = fmaf(a, ez, x.z);
            ew = fmaf(a, ew, x.w);
        }
        const size_t wi = (size_t)(b * CC + sc * CPS + j) * D4 + tid;
        reinterpret_cast<float4*>(csum)[wi] = make_float4(sx, sy, sz, sw);
        reinterpret_cast<float4*>(cend)[wi] = make_float4(ex, ey, ez, ew);
        Sx += sx; Sy += sy; Sz += sz; Sw += sw;
        Ex = fmaf(a16, Ex, ex);
        Ey = fmaf(a16, Ey, ey);
        Ez = fmaf(a16, Ez, ez);
        Ew = fmaf(a16, Ew, ew);
    }
    const size_t wi = (size_t)(b * NSC + sc) * D4 + tid;
    reinterpret_cast<float4*>(ssum)[wi] = make_float4(Sx, Sy, Sz, Sw);
    reinterpret_cast<float4*>(send)[wi] = make_float4(Ex, Ey, Ez, Ew);
}

// ---------------------------------------------------------------------------
// Kernel B: block = (b, chunk). h chunk is stashed to LDS FIRST (max MLP,
// own-thread LDS RAW needs no barrier), then the two-level lookback
// (<=63 superchunk + <=1 chunk stats, L2/LLC-resident, independent loads)
// runs while the h loads drain. Pass A: cumsum + batched butterfly mags.
// Pass B: ctx recurrence from LDS, non-temporal |mag*ctx| store.
// Grid = 8*128 = 1024 blocks x 128 threads; 32 KB LDS -> 4 blocks/CU.
// ---------------------------------------------------------------------------
__global__ __launch_bounds__(D4) void kB_out(
    const float* __restrict__ h, const float* __restrict__ kp,
    const float* __restrict__ csum, const float* __restrict__ cend,
    const float* __restrict__ ssum, const float* __restrict__ send,
    float* __restrict__ out)
{
    const int blk = blockIdx.x;
    const int b = blk / CC, c = blk % CC;
    const int sc = c / CPS, j = c & (CPS - 1);
    const int tid = threadIdx.x;
    const int wave = tid >> 6, lane = tid & 63;
    const float s   = get_s(kp);
    const float a   = expf(-s);
    const float a16 = expf(-s * (float)LL);
    const float aSC = expf(-s * (float)SCT);

    const int t0 = c * LL;
    const float4* hp = reinterpret_cast<const float4*>(h)
                     + (size_t)(b * TT + t0) * D4 + tid;

    __shared__ float4 stash[LL][D4];   // 32 KB chunk stash
    __shared__ float part[2][LL];

    // ---- issue ALL h loads first (16 x 16B per thread, max MLP)
    #pragma unroll
    for (int i = 0; i < LL; i++) stash[i][tid] = hp[(size_t)i * D4];

    float px = 0.f, py = 0.f, pz = 0.f, pw = 0.f;   // h[t0-1]
    if (t0 > 0) {
        float4 pv = *(hp - (ptrdiff_t)D4);
        px = pv.x; py = pv.y; pz = pv.z; pw = pv.w;
    }

    // ---- lookback level 1: superchunks before sc (L2-resident)
    float cox = 0.f, coy = 0.f, coz = 0.f, cow = 0.f;   // cumsum offset
    float ccx = 0.f, ccy = 0.f, ccz = 0.f, ccw = 0.f;   // ctx entering state
    {
        const float4* ss4 = reinterpret_cast<const float4*>(ssum)
                          + (size_t)(b * NSC) * D4 + tid;
        const float4* se4 = reinterpret_cast<const float4*>(send)
                          + (size_t)(b * NSC) * D4 + tid;
        float w = 1.f;
        for (int p = sc - 1; p >= 0; --p) {
            float4 sv = ss4[(size_t)p * D4];
            float4 ev = se4[(size_t)p * D4];
            cox += sv.x; coy += sv.y; coz += sv.z; cow += sv.w;
            ccx = fmaf(w, ev.x, ccx);
            ccy = fmaf(w, ev.y, ccy);
            ccz = fmaf(w, ev.z, ccz);
            ccw = fmaf(w, ev.w, ccw);
            w *= aSC;
        }
    }
    // ---- lookback level 2: chunks before j inside superchunk sc (<=1)
    {
        const float4* cs4 = reinterpret_cast<const float4*>(csum)
                          + (size_t)(b * CC + sc * CPS) * D4 + tid;
        const float4* ce4 = reinterpret_cast<const float4*>(cend)
                          + (size_t)(b * CC + sc * CPS) * D4 + tid;
        float wj = 1.f;
        float cIx = 0.f, cIy = 0.f, cIz = 0.f, cIw = 0.f;
        for (int p = j - 1; p >= 0; --p) {
            float4 sv = cs4[(size_t)p * D4];
            float4 ev = ce4[(size_t)p * D4];
            cox += sv.x; coy += sv.y; coz += sv.z; cow += sv.w;
            cIx = fmaf(wj, ev.x, cIx);
            cIy = fmaf(wj, ev.y, cIy);
            cIz = fmaf(wj, ev.z, cIz);
            cIw = fmaf(wj, ev.w, cIw);
            wj *= a16;
        }
        // ctx entering chunk = (superchunk carry) * a16^j + intra part
        ccx = fmaf(wj, ccx, cIx);
        ccy = fmaf(wj, ccy, cIy);
        ccz = fmaf(wj, ccz, cIz);
        ccw = fmaf(wj, ccw, cIw);
    }

    // ---- pass A: cumsum chain from LDS (own-thread RAW: no barrier needed)
    float r[LL];
    #pragma unroll
    for (int i = 0; i < LL; i++) {
        float4 x = stash[i][tid];
        cox += x.x; coy += x.y; coz += x.z; cow += x.w;
        float dx = cox - px, dy = coy - py, dz = coz - pz, dw = cow - pw;
        r[i] = dx * dx + dy * dy + dz * dz + dw * dw;
        px = x.x; py = x.y; pz = x.z; pw = x.w;
    }

    // batched butterfly: 6 rounds x 16 independent values
    #pragma unroll
    for (int m = 1; m < 64; m <<= 1) {
        #pragma unroll
        for (int i = 0; i < LL; i++) r[i] += __shfl_xor(r[i], m, 64);
    }
    if (lane == 0) {
        #pragma unroll
        for (int i = 0; i < LL; i++) part[wave][i] = r[i];
    }
    __syncthreads();

    float mag[LL];
    #pragma unroll
    for (int i = 0; i < LL; i++) mag[i] = sqrtf(part[0][i] + part[1][i]);

    // ---- pass B: ctx recurrence from LDS, non-temporal output store
    floatx4* op = reinterpret_cast<floatx4*>(out)
                + (size_t)(b * TT + t0) * D4 + tid;
    #pragma unroll
    for (int i = 0; i < LL; i++) {
        float4 x = stash[i][tid];
        ccx = fmaf(a, ccx, x.x);
        ccy = fmaf(a, ccy, x.y);
        ccz = fmaf(a, ccz, x.z);
        ccw = fmaf(a, ccw, x.w);
        float m = mag[i];
        floatx4 o;
        o.x = fabsf(m * ccx); o.y = fabsf(m * ccy);
        o.z = fabsf(m * ccz); o.w = fabsf(m * ccw);
        __builtin_nontemporal_store(o, op + (size_t)i * D4);
    }
}

extern "C" void kernel_launch(void* const* d_in, const int* in_sizes, int n_in,
                              void* d_out, int out_size, void* d_ws, size_t ws_size,
                              hipStream_t stream) {
    const float* h  = (const float*)d_in[0];
    const float* kp = (const float*)d_in[1];
    float* out = (float*)d_out;

    const size_t NC = (size_t)BB * CC * DD;    // 512K floats = 2 MB each
    const size_t NSb = (size_t)BB * NSC * DD;  // 256K floats = 1 MB each
    float* csum = (float*)d_ws;
    float* cend = csum + NC;
    float* ssum = cend + NC;
    float* send = ssum + NSb;

    kA_stats<<<dim3(BB * NSC), dim3(D4), 0, stream>>>(h, kp, csum, cend, ssum, send);
    kB_out  <<<dim3(BB * CC),  dim3(D4), 0, stream>>>(h, kp, csum, cend, ssum, send, out);
}

// Round 10
// 96.504 us; speedup vs baseline: 1.0369x; 1.0369x over previous
//
#include <hip/hip_runtime.h>
#include <math.h>

// Problem constants: h [B,T,D] fp32, k scalar fp32.
#define BB 8
#define TT 2048
#define DD 512
#define LL 16             // chunk length (t-steps)
#define CC (TT / LL)      // 128 chunks per b
#define D4 (DD / 4)       // 128 float4 lanes = block size
#define SCT 64            // superchunk length (t-steps)
#define NSC (TT / SCT)    // 32 superchunks per b
#define CPS (SCT / LL)    // 4 chunks per superchunk

typedef float floatx4 __attribute__((ext_vector_type(4)));

__device__ __forceinline__ float get_s(const float* kp) {
    float k = *kp;
    return (k > 20.0f) ? k : log1pf(expf(k));   // softplus, stable
}

// ---------------------------------------------------------------------------
// Kernel A: block = (b, superchunk). Streams 64 t-steps of h once; emits
// chunk-level stats (sum S, decayed-end E per 16 t) and superchunk-level
// stats (per 64 t). Grid = 8*32 = 256 blocks x 128 threads.  (R8 config)
// ---------------------------------------------------------------------------
__global__ __launch_bounds__(D4) void kA_stats(
    const float* __restrict__ h, const float* __restrict__ kp,
    float* __restrict__ csum, float* __restrict__ cend,
    float* __restrict__ ssum, float* __restrict__ send)
{
    const int blk = blockIdx.x;
    const int b = blk / NSC, sc = blk % NSC;
    const int tid = threadIdx.x;
    const float s   = get_s(kp);
    const float a   = expf(-s);
    const float a16 = expf(-s * (float)LL);

    const float4* hp = reinterpret_cast<const float4*>(h)
                     + (size_t)(b * TT + sc * SCT) * D4 + tid;

    float Sx = 0.f, Sy = 0.f, Sz = 0.f, Sw = 0.f;   // superchunk sum
    float Ex = 0.f, Ey = 0.f, Ez = 0.f, Ew = 0.f;   // superchunk decayed end

    #pragma unroll
    for (int j = 0; j < CPS; j++) {
        float sx = 0.f, sy = 0.f, sz = 0.f, sw = 0.f;
        float ex = 0.f, ey = 0.f, ez = 0.f, ew = 0.f;
        #pragma unroll
        for (int i = 0; i < LL; i++) {
            float4 x = hp[(size_t)(j * LL + i) * D4];
            sx += x.x; sy += x.y; sz += x.z; sw += x.w;
            ex = fmaf(a, ex, x.x);
            ey = fmaf(a, ey, x.y);
            ez = fmaf(a, ez, x.z);
            ew = fmaf(a, ew, x.w);
        }
        const size_t wi = (size_t)(b * CC + sc * CPS + j) * D4 + tid;
        reinterpret_cast<float4*>(csum)[wi] = make_float4(sx, sy, sz, sw);
        reinterpret_cast<float4*>(cend)[wi] = make_float4(ex, ey, ez, ew);
        Sx += sx; Sy += sy; Sz += sz; Sw += sw;
        Ex = fmaf(a16, Ex, ex);
        Ey = fmaf(a16, Ey, ey);
        Ez = fmaf(a16, Ez, ez);
        Ew = fmaf(a16, Ew, ew);
    }
    const size_t wi = (size_t)(b * NSC + sc) * D4 + tid;
    reinterpret_cast<float4*>(ssum)[wi] = make_float4(Sx, Sy, Sz, Sw);
    reinterpret_cast<float4*>(send)[wi] = make_float4(Ex, Ey, Ez, Ew);
}

// ---------------------------------------------------------------------------
// Kernel B: block = (b, chunk). CHANGE vs R8: the h chunk is fetched by
// async global->LDS DMA (width=16) issued BEFORE the lookback, so the
// L2-resident lookback (<=31 superchunk + <=3 chunk stats) overlaps the
// h fetch. Each wave's lanes deposit at stash[i][64w + lane] — exactly the
// region that wave later reads, so one barrier covers the dependency.
// Grid = 8*128 = 1024 blocks x 128 threads; 32 KB LDS -> 4 blocks/CU.
// ---------------------------------------------------------------------------
__global__ __launch_bounds__(D4) void kB_out(
    const float* __restrict__ h, const float* __restrict__ kp,
    const float* __restrict__ csum, const float* __restrict__ cend,
    const float* __restrict__ ssum, const float* __restrict__ send,
    float* __restrict__ out)
{
    const int blk = blockIdx.x;
    const int b = blk / CC, c = blk % CC;
    const int sc = c / CPS, j = c & (CPS - 1);
    const int tid = threadIdx.x;
    const int wave = tid >> 6, lane = tid & 63;
    const int w64 = wave << 6;              // wave-uniform LDS sub-base
    const float s   = get_s(kp);
    const float a   = expf(-s);
    const float a16 = expf(-s * (float)LL);
    const float aSC = expf(-s * (float)SCT);

    const int t0 = c * LL;
    const float4* hp = reinterpret_cast<const float4*>(h)
                     + (size_t)(b * TT + t0) * D4 + tid;

    __shared__ float4 stash[LL][D4];   // 32 KB chunk stash
    __shared__ float part[2][LL];

    // ---- async DMA: h chunk -> LDS, no VGPR round-trip; overlaps lookback
    #pragma unroll
    for (int i = 0; i < LL; i++) {
        __builtin_amdgcn_global_load_lds(
            (const __attribute__((address_space(1))) void*)(hp + (size_t)i * D4),
            (__attribute__((address_space(3))) void*)(&stash[i][w64]),
            16, 0, 0);
    }

    float px = 0.f, py = 0.f, pz = 0.f, pw = 0.f;   // h[t0-1]
    if (t0 > 0) {
        float4 pv = *(hp - (ptrdiff_t)D4);
        px = pv.x; py = pv.y; pz = pv.z; pw = pv.w;
    }

    // ---- lookback level 1: superchunks before sc (L2/LLC-resident)
    float cox = 0.f, coy = 0.f, coz = 0.f, cow = 0.f;   // cumsum offset
    float ccx = 0.f, ccy = 0.f, ccz = 0.f, ccw = 0.f;   // ctx entering state
    {
        const float4* ss4 = reinterpret_cast<const float4*>(ssum)
                          + (size_t)(b * NSC) * D4 + tid;
        const float4* se4 = reinterpret_cast<const float4*>(send)
                          + (size_t)(b * NSC) * D4 + tid;
        float w = 1.f;
        for (int p = sc - 1; p >= 0; --p) {
            float4 sv = ss4[(size_t)p * D4];
            float4 ev = se4[(size_t)p * D4];
            cox += sv.x; coy += sv.y; coz += sv.z; cow += sv.w;
            ccx = fmaf(w, ev.x, ccx);
            ccy = fmaf(w, ev.y, ccy);
            ccz = fmaf(w, ev.z, ccz);
            ccw = fmaf(w, ev.w, ccw);
            w *= aSC;
        }
    }
    // ---- lookback level 2: chunks before j inside superchunk sc (<=3)
    {
        const float4* cs4 = reinterpret_cast<const float4*>(csum)
                          + (size_t)(b * CC + sc * CPS) * D4 + tid;
        const float4* ce4 = reinterpret_cast<const float4*>(cend)
                          + (size_t)(b * CC + sc * CPS) * D4 + tid;
        float wj = 1.f;
        float cIx = 0.f, cIy = 0.f, cIz = 0.f, cIw = 0.f;
        for (int p = j - 1; p >= 0; --p) {
            float4 sv = cs4[(size_t)p * D4];
            float4 ev = ce4[(size_t)p * D4];
            cox += sv.x; coy += sv.y; coz += sv.z; cow += sv.w;
            cIx = fmaf(wj, ev.x, cIx);
            cIy = fmaf(wj, ev.y, cIy);
            cIz = fmaf(wj, ev.z, cIz);
            cIw = fmaf(wj, ev.w, cIw);
            wj *= a16;
        }
        // ctx entering chunk = (superchunk carry) * a16^j + intra part
        ccx = fmaf(wj, ccx, cIx);
        ccy = fmaf(wj, ccy, cIy);
        ccz = fmaf(wj, ccz, cIz);
        ccw = fmaf(wj, ccw, cIw);
    }

    __syncthreads();   // drains the DMA (vmcnt) before LDS reads

    // ---- pass A: cumsum chain from LDS
    float r[LL];
    #pragma unroll
    for (int i = 0; i < LL; i++) {
        float4 x = stash[i][tid];
        cox += x.x; coy += x.y; coz += x.z; cow += x.w;
        float dx = cox - px, dy = coy - py, dz = coz - pz, dw = cow - pw;
        r[i] = dx * dx + dy * dy + dz * dz + dw * dw;
        px = x.x; py = x.y; pz = x.z; pw = x.w;
    }

    // batched butterfly: 6 rounds x 16 independent values
    #pragma unroll
    for (int m = 1; m < 64; m <<= 1) {
        #pragma unroll
        for (int i = 0; i < LL; i++) r[i] += __shfl_xor(r[i], m, 64);
    }
    if (lane == 0) {
        #pragma unroll
        for (int i = 0; i < LL; i++) part[wave][i] = r[i];
    }
    __syncthreads();

    float mag[LL];
    #pragma unroll
    for (int i = 0; i < LL; i++) mag[i] = sqrtf(part[0][i] + part[1][i]);

    // ---- pass B: ctx recurrence from LDS, non-temporal output store
    floatx4* op = reinterpret_cast<floatx4*>(out)
                + (size_t)(b * TT + t0) * D4 + tid;
    #pragma unroll
    for (int i = 0; i < LL; i++) {
        float4 x = stash[i][tid];
        ccx = fmaf(a, ccx, x.x);
        ccy = fmaf(a, ccy, x.y);
        ccz = fmaf(a, ccz, x.z);
        ccw = fmaf(a, ccw, x.w);
        float m = mag[i];
        floatx4 o;
        o.x = fabsf(m * ccx); o.y = fabsf(m * ccy);
        o.z = fabsf(m * ccz); o.w = fabsf(m * ccw);
        __builtin_nontemporal_store(o, op + (size_t)i * D4);
    }
}

extern "C" void kernel_launch(void* const* d_in, const int* in_sizes, int n_in,
                              void* d_out, int out_size, void* d_ws, size_t ws_size,
                              hipStream_t stream) {
    const float* h  = (const float*)d_in[0];
    const float* kp = (const float*)d_in[1];
    float* out = (float*)d_out;

    const size_t NC = (size_t)BB * CC * DD;    // 512K floats = 2 MB each
    const size_t NSb = (size_t)BB * NSC * DD;  // 128K floats = 512 KB each
    float* csum = (float*)d_ws;
    float* cend = csum + NC;
    float* ssum = cend + NC;
    float* send = ssum + NSb;

    kA_stats<<<dim3(BB * NSC), dim3(D4), 0, stream>>>(h, kp, csum, cend, ssum, send);
    kB_out  <<<dim3(BB * CC),  dim3(D4), 0, stream>>>(h, kp, csum, cend, ssum, send, out);
}